// Round 9
// baseline (516.150 us; speedup 1.0000x reference)
//
#include <hip/hip_runtime.h>
#include <cstdint>
#include <cstddef>

// ---------------- problem constants ----------------
#define B_  2
#define S_  4096
#define H_  2048
#define L_  2048
#define NH_ 16
#define M_  (B_*S_)     // 8192 rows
#define NC_ 64          // scan chunks
#define CS_ 64          // chunk size (NC_*CS_ == S_)

typedef unsigned short u16;
typedef short  bf8v  __attribute__((ext_vector_type(8)));   // 8 bf16 as raw shorts (MFMA operand)
typedef u16    u16x8 __attribute__((ext_vector_type(8)));
typedef float  f32x4 __attribute__((ext_vector_type(4)));

__device__ __forceinline__ float bf2f(u16 u){
  union { unsigned i; float f; } v; v.i = ((unsigned)u) << 16; return v.f;
}
__device__ __forceinline__ u16 f2bf(float f){
  union { float f; unsigned i; } v; v.f = f;
  unsigned u = v.i;
  return (u16)((u + 0x7FFFu + ((u >> 16) & 1u)) >> 16);   // RNE
}
__device__ __forceinline__ float bfr(float f){ return bf2f(f2bf(f)); }  // round to bf16
__device__ __forceinline__ void gld16(const void* g, void* l){
  __builtin_amdgcn_global_load_lds((const __attribute__((address_space(1))) void*)g,
                                   (__attribute__((address_space(3))) void*)l, 16, 0, 0);
}
__device__ __forceinline__ unsigned ldsoff(const void* p){
  return (unsigned)(uintptr_t)(const __attribute__((address_space(3))) void*)p;
}
template<int IMM>
__device__ __forceinline__ bf8v dsr(unsigned addr){
  bf8v r;
  asm volatile("ds_read_b128 %0, %1 offset:%c2" : "=v"(r) : "v"(addr), "i"(IMM));
  return r;
}

#define SB0_()     __builtin_amdgcn_sched_barrier(0)
#define BARRIER_() do{ __builtin_amdgcn_s_barrier(); SB0_(); }while(0)
#define LGKM0_()   do{ asm volatile("s_waitcnt lgkmcnt(0)" ::: "memory"); SB0_(); }while(0)
#define VMC8_()    do{ asm volatile("s_waitcnt vmcnt(8)" ::: "memory"); SB0_(); }while(0)

// ============================================================================
// 256x256 8-phase GEMM, v3: REGISTER READ-AHEAD (LDS drain under MFMA).
// Staging ledger identical to R5 (race-free-proven): per tile t (buf D):
//   Ph3 stg: B(t+2)h0 -> D;  Ph4 stg: B(t+2)h1 + A(t+2)h0,h1 -> D; vmcnt(8)
//   (retires tile t+1's 8 loads; 2-tile-deep pipeline, seeded by prologue).
// NEW read/wait schedule: each phase ISSUES next quadrant's ds_reads, then
// MFMAs the quadrant read LAST phase, then lgkmcnt(0) AFTER the MFMA -> the
// 8-wave LDS queue drains under the MFMA cluster instead of before it.
// Quadrants: Q(0,0)[a,b01] -> Q(0,1)[a,b23] -> Q(1,0)[aN,b01] -> Q(1,1)[aN,b23].
// Ph4 reads next-tile A0->a, B0->b01 from buf 1-D, strictly AFTER vmcnt(8)
// (tile t+1 landed). 3 barriers/tile; every stg-vs-read hazard separated by
// >=1 barrier after the corresponding lgkmcnt drain (audited per pair).
// ============================================================================
struct StageCtx { const u16* sA; const u16* sB; int lda; int K; char* ldsc; unsigned dst; };

__device__ __forceinline__ void stgA(const StageCtx& c, int buf, int h, int tile){
#pragma unroll
  for (int r=0;r<2;r++){
    int rr = h*128 + r*64;
    gld16(c.sA + (size_t)rr*c.lda + (size_t)tile*64, c.ldsc + buf*32768 + c.dst + rr*128);
  }
}
__device__ __forceinline__ void stgB(const StageCtx& c, int buf, int h, int tile){
#pragma unroll
  for (int r=0;r<2;r++){
    int rr = h*128 + r*64;
    gld16(c.sB + (size_t)rr*c.K + (size_t)tile*64, c.ldsc + 65536 + buf*32768 + c.dst + rr*128);
  }
}

#define MFMAQ(ARR, MH, NHH) do{                                                 \
  __builtin_amdgcn_s_setprio(1);                                                \
  _Pragma("unroll") for (int ks=0;ks<2;ks++)                                    \
  _Pragma("unroll") for (int dm=0;dm<4;dm++)                                    \
  _Pragma("unroll") for (int dn=0;dn<2;dn++)                                    \
    acc[(MH)*4+dm][(NHH)*2+dn] = __builtin_amdgcn_mfma_f32_16x16x32_bf16(       \
        ARR[dm][ks], b[(NHH)*2+dn][ks], acc[(MH)*4+dm][(NHH)*2+dn], 0,0,0);     \
  __builtin_amdgcn_s_setprio(0);                                                \
}while(0)

template<int D>
__device__ __forceinline__ void tile_phase(
    bf8v (&a)[4][2], bf8v (&aN)[4][2], bf8v (&b)[4][2], f32x4 (&acc)[8][4],
    unsigned aA0, unsigned aA1, unsigned aB0, unsigned aB1,
    const StageCtx& ctx, int tp2)
{
  constexpr int DB = D*32768;
  constexpr int OB = (1-D)*32768;
  // ---- Ph1: issue B1(t)->b23; MFMA Q(0,0) [a,b01]; drain; barrier
  b[2][0]=dsr<DB+4096>(aB0); b[2][1]=dsr<DB+4096>(aB1);
  b[3][0]=dsr<DB+6144>(aB0); b[3][1]=dsr<DB+6144>(aB1);
  SB0_();
  MFMAQ(a, 0, 0);
  LGKM0_(); BARRIER_();
  // ---- Ph2: issue A1(t)->aN; MFMA Q(0,1) [a,b23]; drain; barrier
  aN[0][0]=dsr<DB+ 8192>(aA0); aN[0][1]=dsr<DB+ 8192>(aA1);
  aN[1][0]=dsr<DB+10240>(aA0); aN[1][1]=dsr<DB+10240>(aA1);
  aN[2][0]=dsr<DB+12288>(aA0); aN[2][1]=dsr<DB+12288>(aA1);
  aN[3][0]=dsr<DB+14336>(aA0); aN[3][1]=dsr<DB+14336>(aA1);
  SB0_();
  MFMAQ(a, 0, 1);
  LGKM0_(); BARRIER_();
  // ---- Ph3: stg B(t+2)h0 -> buf D; MFMA Q(1,0) [aN,b01]  (no reads, no barrier)
  stgB(ctx, D, 0, tp2);
  SB0_();
  MFMAQ(aN, 1, 0);
  SB0_();
  // ---- Ph4: stg rest -> buf D; vmcnt(8); issue next-tile A0->a, B0->b01
  //      (buf 1-D, landed); MFMA Q(1,1) [aN,b23]; drain; barrier
  stgB(ctx, D, 1, tp2);
  stgA(ctx, D, 0, tp2);
  stgA(ctx, D, 1, tp2);
  VMC8_();
  a[0][0]=dsr<OB+   0>(aA0); a[0][1]=dsr<OB+   0>(aA1);
  a[1][0]=dsr<OB+2048>(aA0); a[1][1]=dsr<OB+2048>(aA1);
  a[2][0]=dsr<OB+4096>(aA0); a[2][1]=dsr<OB+4096>(aA1);
  a[3][0]=dsr<OB+6144>(aA0); a[3][1]=dsr<OB+6144>(aA1);
  b[0][0]=dsr<OB+   0>(aB0); b[0][1]=dsr<OB+   0>(aB1);
  b[1][0]=dsr<OB+2048>(aB0); b[1][1]=dsr<OB+2048>(aB1);
  SB0_();
  MFMAQ(aN, 1, 1);
  LGKM0_(); BARRIER_();
}

__global__ __launch_bounds__(512)
void gemm256p(const u16* __restrict__ A, int lda,
              const u16* __restrict__ Bt, int K,
              const float* __restrict__ bias1, const float* __restrict__ bias2,
              void* __restrict__ C1, u16* __restrict__ C2, int ldc,
              int gelu_flag, int f32out)
{
  __shared__ __align__(16) u16 lds[65536];   // 128 KB: [A0][A1][B0][B1]
  const int t    = threadIdx.x;
  const int lane = t & 63;
  const int w    = t >> 6;
  const int wm   = w >> 2, wn = w & 3;
  const int lr   = lane & 15, lk = lane >> 4;

  // XCD-aware bijective swizzle (grid counts are multiples of 8)
  const int nwg = gridDim.x * gridDim.y;
  const int bid = blockIdx.y * gridDim.x + blockIdx.x;
  const int cpx = nwg >> 3;
  const int swz = (bid & 7) * cpx + (bid >> 3);
  const int bx  = swz % gridDim.x;
  const int by  = swz / gridDim.x;

  const long rowA0 = (long)by * 256;
  const long colB0 = (long)bx * 256;
  const u16* Ag = A  + rowA0 * lda;
  const u16* Bg = Bt + colB0 * K;

  char* ldsc = (char*)lds;
  StageCtx ctx;
  ctx.sA  = Ag + (size_t)(t>>3)*lda + ((t&7) ^ ((t>>3)&7))*8;
  ctx.sB  = Bg + (size_t)(t>>3)*K   + ((t&7) ^ ((t>>3)&7))*8;
  ctx.lda = lda; ctx.K = K; ctx.ldsc = ldsc;
  ctx.dst = (unsigned)((t>>3)*128 + (t&7)*16);

  const unsigned lb  = ldsoff(lds);
  const unsigned swx = (unsigned)((lr & 7) << 4);
  const unsigned aA0 = lb + (wm*128 + lr)*128 + ((      lk*16) ^ swx);
  const unsigned aA1 = lb + (wm*128 + lr)*128 + ((64 +  lk*16) ^ swx);
  const unsigned aB0 = lb + 65536 + (wn*64 + lr)*128 + ((      lk*16) ^ swx);
  const unsigned aB1 = lb + 65536 + (wn*64 + lr)*128 + ((64 +  lk*16) ^ swx);

  f32x4 acc[8][4];
#pragma unroll
  for (int m=0;m<8;m++)
#pragma unroll
    for (int n=0;n<4;n++) acc[m][n] = (f32x4){0.f,0.f,0.f,0.f};
  bf8v a[4][2], aN[4][2], b[4][2];

  const int nkt = K / 64;
  // prologue: tile0 -> buf0, tile1 -> buf1 (8+8 loads); await tile0; prime regs.
  stgB(ctx, 0, 0, 0);        stgB(ctx, 0, 1, 0);
  stgA(ctx, 0, 0, 0);        stgA(ctx, 0, 1, 0);
  stgB(ctx, 1, 0, 1 % nkt);  stgB(ctx, 1, 1, 1 % nkt);
  stgA(ctx, 1, 0, 1 % nkt);  stgA(ctx, 1, 1, 1 % nkt);
  VMC8_();
  BARRIER_();
  a[0][0]=dsr<   0>(aA0); a[0][1]=dsr<   0>(aA1);
  a[1][0]=dsr<2048>(aA0); a[1][1]=dsr<2048>(aA1);
  a[2][0]=dsr<4096>(aA0); a[2][1]=dsr<4096>(aA1);
  a[3][0]=dsr<6144>(aA0); a[3][1]=dsr<6144>(aA1);
  b[0][0]=dsr<   0>(aB0); b[0][1]=dsr<   0>(aB1);
  b[1][0]=dsr<2048>(aB0); b[1][1]=dsr<2048>(aB1);
  LGKM0_();

  for (int i = 0; i < nkt/2; ++i) {
    int t0 = 2*i;
    tile_phase<0>(a, aN, b, acc, aA0, aA1, aB0, aB1, ctx, (t0+2)%nkt);
    tile_phase<1>(a, aN, b, acc, aA0, aA1, aB0, aB1, ctx, (t0+3)%nkt);
  }

  // epilogue: C/D layout col=lane&15, row=(lane>>4)*4+reg (m89-verified)
  u16*   Cb = (u16*)C1;
  float* Cf = (float*)C1;
  const long rowW = rowA0 + wm*128;
  const int  colW = (int)colB0 + wn*64;
#pragma unroll
  for (int mf=0;mf<8;mf++){
    long row = rowW + mf*16 + lk*4;
#pragma unroll
    for (int nf=0;nf<4;nf++){
      int col = colW + nf*16 + lr;
      bool sec = (C2 != nullptr) && (col >= L_);
      float bvv = sec ? bias2[col - L_] : bias1[col];
      bool gel = gelu_flag && !sec;
#pragma unroll
      for (int rr=0; rr<4; ++rr){
        float v = acc[mf][nf][rr] + bvv;
        if (gel) {
          float u  = 0.7978845608028654f * (v + 0.044715f * v*v*v);
          float tu = fminf(fmaxf(2.f*u, -80.f), 80.f);
          float e  = __expf(tu);
          float th = (e - 1.f) / (e + 1.f);
          v = 0.5f * v * (1.f + th);
        }
        if (sec)          C2[(row+rr)*(long)L_ + (col - L_)] = f2bf(v);
        else if (f32out)  Cf[(row+rr)*(long)ldc + col] = v;
        else              Cb[(row+rr)*(long)ldc + col] = f2bf(v);
      }
    }
  }
}

// ============================================================================
// gates_fused (verified R6/R7/R8): conv + block-diag gate GEMM + pointwise +
// chunk summaries.
// ============================================================================
__global__ __launch_bounds__(256)
void gates_fused(const u16* __restrict__ Xlin, const float* __restrict__ cw,
                 const float* __restrict__ cb, const u16* __restrict__ Gt,
                 const float* __restrict__ gbias, const float* __restrict__ c8,
                 const int* __restrict__ pos,
                 u16* __restrict__ Ae, u16* __restrict__ Nr,
                 float* __restrict__ Ach, float* __restrict__ Hch)
{
  __shared__ __align__(16) char sm[16384 + 32768];   // [xc 16KB][xs/bs 32KB]
  const int t  = threadIdx.x;
  const int sc = blockIdx.x;      // seq chunk 0..63
  const int n  = blockIdx.y;      // head 0..15
  const int b  = blockIdx.z;      // batch
  const int s0 = sc*64;
  const long rowg0 = (long)b*S_ + s0;

  char* xc = sm;                  // [64][256B] swizzled conv output (A-operand + x)
  u16*  xs = (u16*)(sm + 16384);  // [67][128] linear staging of Xlin
  char* bs = sm + 16384;          // [128][256B] swizzled weights (after conv)

  // ---- 1) stage Xlin tile with halo (67 rows x 16 chunks of 8 ch)
  for (int it=0; it<5; ++it){
    int slot = it*256 + t;
    if (slot < 67*16){
      int i = slot >> 4, c = slot & 15;
      int s = s0 - 3 + i;
      u16x8 v = (u16x8){0,0,0,0,0,0,0,0};
      if (s >= 0)
        v = *(const u16x8*)(Xlin + ((long)b*S_ + s)*L_ + n*128 + c*8);
      *(u16x8*)(xs + i*128 + c*8) = v;
    }
  }
  __syncthreads();

  // ---- 2) conv -> xc (XOR-swizzled rows of 256B)
#pragma unroll
  for (int it=0; it<4; ++it){
    int slot = it*256 + t;              // 64*16 = 1024 slots
    int row = slot >> 4, c = slot & 15;
    int d0 = c*8;
    float a8[8];
#pragma unroll
    for (int j=0;j<8;j++) a8[j] = cb[n*128 + d0 + j];
#pragma unroll
    for (int k=0;k<4;k++){
      u16x8 xv = *(const u16x8*)(xs + (row+k)*128 + d0);
#pragma unroll
      for (int j=0;j<8;j++)
        a8[j] += bf2f(xv[j]) * cw[(n*128 + d0 + j)*4 + k];
    }
    u16x8 o;
#pragma unroll
    for (int j=0;j<8;j++) o[j] = f2bf(a8[j]);
    *(u16x8*)(xc + row*256 + ((d0*2) ^ ((row&7)<<4))) = o;
  }
  __syncthreads();   // conv reads of xs done; bs may overwrite

  const int w  = t >> 6;          // wave 0..3 -> rows w*16..+16
  const int lane = t & 63;
  const int lr = lane & 15, lk = lane >> 4;
  const int arow = w*16 + lr;

  // A-frags from xc (K=128 -> 4 k-steps)
  bf8v af[4];
#pragma unroll
  for (int ks=0;ks<4;ks++)
    af[ks] = *(const bf8v*)(xc + arow*256 + ((ks*64 + lk*16) ^ ((arow&7)<<4)));

  f32x4 aig[8], brg[8];
#pragma unroll
  for (int half=0; half<2; ++half){
    // ---- 3a) stage weight half (pre-swizzled source, linear LDS dest)
#pragma unroll
    for (int it=0; it<8; ++it){
      int slot = it*256 + t;            // 128*16 = 2048 slots
      int jr = slot >> 4, c = slot & 15;
      gld16(Gt + (size_t)(n*256 + half*128 + jr)*128 + (size_t)((c ^ (jr&7))*8),
            bs + slot*16);
    }
    __syncthreads();                    // drains vmcnt(0): weights landed
    // ---- 3b) MFMA
#pragma unroll
    for (int nf=0; nf<8; ++nf){
      f32x4 acc = (f32x4){0.f,0.f,0.f,0.f};
      int jrow = nf*16 + lr;
#pragma unroll
      for (int ks=0;ks<4;ks++){
        bf8v bv = *(const bf8v*)(bs + jrow*256 + ((ks*64 + lk*16) ^ ((jrow&7)<<4)));
        acc = __builtin_amdgcn_mfma_f32_16x16x32_bf16(af[ks], bv, acc, 0, 0, 0);
      }
      if (half==0) aig[nf] = acc; else brg[nf] = acc;
    }
    __syncthreads();                    // b-frag reads done before next overwrite
  }

  // ---- 4) pointwise epilogue + per-channel chunk summary.
  float* wsA = (float*)bs;              // [4 waves][128 ch]
  float* wsh = (float*)(bs + 2048);     // [4 waves][128 ch]
  bool rst[4];
#pragma unroll
  for (int rr=0; rr<4; ++rr) rst[rr] = (pos[rowg0 + w*16 + lk*4 + rr] == 0);

#pragma unroll
  for (int nf=0; nf<8; ++nf){
    int dl = nf*16 + lr;
    float gb1 = gbias[n*256 + dl];
    float gb2 = gbias[n*256 + 128 + dl];
    float cc8 = c8[n*128 + dl];
    float Aseg = 1.f, hseg = 0.f;       // ordered scan over rr = rows lk*4..+3
#pragma unroll
    for (int rr=0; rr<4; ++rr){
      int row = w*16 + lk*4 + rr;
      long gs = rowg0 + row;
      float ig = 1.f / (1.f + __expf(-(aig[nf][rr] + gb1)));
      float rg = 1.f / (1.f + __expf(-(brg[nf][rr] + gb2)));
      float la = cc8 * rg;
      float a  = __expf(la);
      float mult = rst[rr] ? 1.f : sqrtf(fmaxf(1.f - __expf(2.f*la), 0.f));
      u16 xv = *(const u16*)(xc + row*256 + ((dl*2) ^ ((row&7)<<4)));
      float x = bf2f(xv);
      float nrv = bfr(x * ig * mult);          // bf16-rounded (matches stored value)
      float aev = rst[rr] ? 0.f : bfr(a);
      Nr[gs*L_ + n*128 + dl] = f2bf(nrv);
      Ae[gs*L_ + n*128 + dl] = f2bf(aev);
      hseg = fmaf(aev, hseg, nrv);
      Aseg *= aev;
    }
    // ordered compose across lk (4-row segments -> 16-row wave segment)
    {
      float Ap = __shfl_xor(Aseg, 16);
      float hp = __shfl_xor(hseg, 16);
      bool low = ((lk & 1) == 0);
      float Alo = low ? Aseg : Ap, Ahi = low ? Ap : Aseg;
      float hlo = low ? hseg : hp, hhi = low ? hp : hseg;
      Aseg = Alo * Ahi; hseg = fmaf(Ahi, hlo, hhi);
      Ap = __shfl_xor(Aseg, 32);
      hp = __shfl_xor(hseg, 32);
      low = ((lk & 2) == 0);
      Alo = low ? Aseg : Ap; Ahi = low ? Ap : Aseg;
      hlo = low ? hseg : hp; hhi = low ? hp : hseg;
      Aseg = Alo * Ahi; hseg = fmaf(Ahi, hlo, hhi);
    }
    if (lk == 0){ wsA[w*128 + dl] = Aseg; wsh[w*128 + dl] = hseg; }
  }
  __syncthreads();
  if (t < 128){
    float A = wsA[t], h = wsh[t];
#pragma unroll
    for (int ww=1; ww<4; ++ww){
      float Aw = wsA[ww*128 + t], hw = wsh[ww*128 + t];
      h = fmaf(Aw, h, hw);
      A *= Aw;
    }
    long o = ((long)b*NC_ + sc)*L_ + n*128 + t;
    Ach[o] = A; Hch[o] = h;
  }
}

// ============================================================================
// prep_all (verified R8): transposes + gate-pack + X->bf16 in one launch
// ============================================================================
__global__ __launch_bounds__(256)
void prep_all(const float* __restrict__ Wy, const float* __restrict__ Wx,
              const float* __restrict__ Wout,
              u16* __restrict__ WyT, u16* __restrict__ WxT, u16* __restrict__ WoT,
              const float* __restrict__ igw, const float* __restrict__ rgw,
              const float* __restrict__ igb, const float* __restrict__ rgb,
              const float* __restrict__ rec, u16* __restrict__ Gt,
              float* __restrict__ gbias, float* __restrict__ c8,
              const float* __restrict__ X, u16* __restrict__ Xb)
{
  const int bidg = blockIdx.x;
  const int t = threadIdx.x;
  if (bidg < 3072) {
    int z   = bidg >> 10;
    int rem = bidg & 1023;
    const float* in  = (z == 0) ? Wy  : (z == 1) ? Wx  : Wout;
    u16*         out = (z == 0) ? WyT : (z == 1) ? WxT : WoT;
    const int R = 2048, C = 2048;
    __shared__ float tile[64][65];
    int tc = (rem & 31) * 64, tr = (rem >> 5) * 64;
    int r  = t >> 2, c0 = (t & 3) * 16;
#pragma unroll
    for (int i=0;i<4;i++)
      *(f32x4*)(&tile[r][c0 + i*4]) = *(const f32x4*)(in + (long)(tr+r)*C + tc + c0 + i*4);
    __syncthreads();
    int nl = t >> 2;
#pragma unroll
    for (int it=0; it<2; ++it){
      int g = (t & 3) + it*4;
      u16x8 o;
#pragma unroll
      for (int e=0;e<8;e++) o[e] = f2bf(tile[g*8+e][nl]);
      *(u16x8*)(out + (long)(tc+nl)*R + tr + g*8) = o;
    }
  } else if (bidg < 5120) {
    int idx = (bidg - 3072)*256 + t;       // NH_*256*128 = 524288
    int d = idx & 127, g = idx >> 7;
    int n = g >> 8, j = g & 255;
    float v = (j < 128) ? igw[(n*128 + d)*128 + j] : rgw[(n*128 + d)*128 + (j-128)];
    Gt[idx] = f2bf(v);
    if (idx < NH_*256) {
      int nn = idx >> 8, jj = idx & 255;
      gbias[idx] = (jj < 128) ? igb[nn*128 + jj] : rgb[nn*128 + jj - 128];
    }
    if (idx < L_) c8[idx] = -8.f * log1pf(__expf(rec[idx]));
  } else {
    long idx = (long)(bidg - 5120)*256 + t;
    f32x4 a = *(const f32x4*)(X + idx*8);
    f32x4 b = *(const f32x4*)(X + idx*8 + 4);
    u16x8 o;
#pragma unroll
    for (int e=0;e<4;e++){ o[e] = f2bf(a[e]); o[4+e] = f2bf(b[e]); }
    *(u16x8*)(Xb + idx*8) = o;
  }
}

// ---------------- scan3 (verified R8): carry prefix + recompute + Z = h*y ----------------
__global__ __launch_bounds__(256)
void scan3(const u16* __restrict__ Ae, const u16* __restrict__ Nr,
           const float* __restrict__ Ach, const float* __restrict__ Hch,
           const u16* __restrict__ Y, u16* __restrict__ Z)
{
  int t = threadIdx.x;
  int l = (blockIdx.x & 7)*256 + t;
  int c = (NC_-1) - ((blockIdx.x >> 3) & (NC_-1));
  int b = blockIdx.x >> 9;
  float h = 0.f;
#pragma unroll 4
  for (int cc = 0; cc < c; ++cc){
    long o = ((long)b*NC_ + cc)*L_ + l;
    h = fmaf(Ach[o], h, Hch[o]);
  }
  long base = ((long)b*S_ + (long)c*CS_)*L_ + l;
#pragma unroll 8
  for (int s=0; s<CS_; ++s){
    long o = base + (long)s*L_;
    h = fmaf(bf2f(Ae[o]), h, bf2f(Nr[o]));
    Z[o] = f2bf(h * bf2f(Y[o]));
  }
}

// ---------------- launch ----------------
extern "C" void kernel_launch(void* const* d_in, const int* in_sizes, int n_in,
                              void* d_out, int out_size, void* d_ws, size_t ws_size,
                              hipStream_t stream)
{
  (void)in_sizes; (void)n_in; (void)out_size; (void)ws_size;
  const float* X    = (const float*)d_in[0];
  const float* Wy   = (const float*)d_in[1];
  const float* by   = (const float*)d_in[2];
  const float* Wx   = (const float*)d_in[3];
  const float* bx   = (const float*)d_in[4];
  const float* cw   = (const float*)d_in[5];
  const float* cb   = (const float*)d_in[6];
  const float* rec  = (const float*)d_in[7];
  const float* igw  = (const float*)d_in[8];
  const float* igb  = (const float*)d_in[9];
  const float* rgw  = (const float*)d_in[10];
  const float* rgb  = (const float*)d_in[11];
  const float* Wout = (const float*)d_in[12];
  const float* bout = (const float*)d_in[13];
  const int*   pos  = (const int*)d_in[14];
  float* out = (float*)d_out;   // reference output dtype is float32

  char* ws = (char*)d_ws;
  size_t o_Xbf  = 0;
  size_t o_Xlin = o_Xbf  + (size_t)M_*H_*2;
  size_t o_WyT  = o_Xlin + (size_t)M_*L_*2;           // WyT then WxT contiguous => fused Bt
  size_t o_WxT  = o_WyT  + (size_t)H_*L_*2;
  size_t o_WoT  = o_WxT  + (size_t)H_*L_*2;
  size_t o_Gt   = o_WoT  + (size_t)L_*H_*2;
  size_t o_gb   = o_Gt   + (size_t)NH_*256*128*2;
  size_t o_c8   = o_gb   + 4096*4;
  size_t o_Y    = o_c8   + 2048*4;
  size_t o_xc   = o_Y    + (size_t)M_*L_*2;           // Z buffer region
  size_t o_Ae   = o_xc   + (size_t)M_*L_*2;
  size_t o_Nr   = o_Ae   + (size_t)M_*L_*2;
  size_t o_Ach  = o_Nr   + (size_t)M_*L_*2;
  size_t o_Hch  = o_Ach  + (size_t)B_*NC_*L_*4;

  u16*   Xbf   = (u16*)(ws + o_Xbf);
  u16*   Xlin  = (u16*)(ws + o_Xlin);
  u16*   WyT   = (u16*)(ws + o_WyT);
  u16*   WxT   = (u16*)(ws + o_WxT);
  u16*   WoT   = (u16*)(ws + o_WoT);
  u16*   Gt    = (u16*)(ws + o_Gt);
  float* gbias = (float*)(ws + o_gb);
  float* c8    = (float*)(ws + o_c8);
  u16*   Y     = (u16*)(ws + o_Y);
  u16*   Z     = (u16*)(ws + o_xc);
  u16*   Ae    = (u16*)(ws + o_Ae);
  u16*   Nr    = (u16*)(ws + o_Nr);
  float* Ach   = (float*)(ws + o_Ach);
  float* Hch   = (float*)(ws + o_Hch);

  dim3 blk(256);
  // merged prep
  prep_all<<<dim3(13312), blk, 0, stream>>>(Wy, Wx, Wout, WyT, WxT, WoT,
                                            igw, rgw, igb, rgb, rec, Gt, gbias, c8,
                                            X, Xbf);
  // fused y+x linears (8-phase v3): Bt = [WyT ; WxT], N=4096
  gemm256p<<<dim3(16,32), dim3(512), 0, stream>>>(Xbf, H_, WyT, H_, by, bx, Y, Xlin, L_, 1, 0);
  // fused conv + block-diag gate GEMM + pointwise + chunk summaries
  gates_fused<<<dim3(NC_, NH_, B_), blk, 0, stream>>>(Xlin, cw, cb, Gt, gbias, c8, pos,
                                                      Ae, Nr, Ach, Hch);
  // carry prefix + recompute + Z = h*y (c-reversed dispatch)
  scan3<<<dim3(1024), blk, 0, stream>>>(Ae, Nr, Ach, Hch, Y, Z);
  // output projection (8-phase v3) into d_out (fp32)
  gemm256p<<<dim3(8,32), dim3(512), 0, stream>>>(Z, L_, WoT, L_, bout, bout, out, nullptr, H_, 0, 1);
}

// Round 10
// 403.915 us; speedup vs baseline: 1.2779x; 1.2779x over previous
//
#include <hip/hip_runtime.h>
#include <cstdint>
#include <cstddef>

// ---------------- problem constants ----------------
#define B_  2
#define S_  4096
#define H_  2048
#define L_  2048
#define NH_ 16
#define M_  (B_*S_)     // 8192 rows
#define NC_ 64          // scan chunks
#define CS_ 64          // chunk size (NC_*CS_ == S_)

typedef unsigned short u16;
typedef unsigned int   u32;
typedef short  bf8v  __attribute__((ext_vector_type(8)));   // 8 bf16 as raw shorts (MFMA operand)
typedef u16    u16x8 __attribute__((ext_vector_type(8)));
typedef u16    u16x4 __attribute__((ext_vector_type(4)));
typedef float  f32x4 __attribute__((ext_vector_type(4)));

__device__ __forceinline__ float bf2f(u16 u){
  union { unsigned i; float f; } v; v.i = ((unsigned)u) << 16; return v.f;
}
__device__ __forceinline__ u16 f2bf(float f){
  union { float f; unsigned i; } v; v.f = f;
  unsigned u = v.i;
  return (u16)((u + 0x7FFFu + ((u >> 16) & 1u)) >> 16);   // RNE
}
__device__ __forceinline__ float bfr(float f){ return bf2f(f2bf(f)); }  // round to bf16
__device__ __forceinline__ void gld16(const void* g, void* l){
  __builtin_amdgcn_global_load_lds((const __attribute__((address_space(1))) void*)g,
                                   (__attribute__((address_space(3))) void*)l, 16, 0, 0);
}

// ---------------- GEMM: C[M,N] = A[M,K](bf16) @ Bt[N,K](bf16)^T, + bias, opt gelu ----------
// VERIFIED (rounds 2/3/6/7/8). BM=BN=128, BK=64, 256 thr (4 waves 2x2), 4x4 16x16x32 frags.
// Per K-step: ds_read all frags -> barrier -> issue next-tile global_load_lds -> MFMA
// (prefetch lands under MFMA) -> syncthreads. XCD M-band swizzle for L2 residency.
// 8 blocks/CU give the TLP that hides staging latency (the 256^2 1-block/CU
// experiments R4/R5/R9 all converged to schedule-invariant ~2.5x slower).
__global__ __launch_bounds__(256)
void gemm_bf16(const u16* __restrict__ A, int lda,
               const u16* __restrict__ Bt, int K,
               const float* __restrict__ bias1, const float* __restrict__ bias2,
               void* __restrict__ C1, u16* __restrict__ C2, int ldc,
               int gelu_flag, int f32out)
{
  __shared__ u16 Alds[128*64];
  __shared__ u16 Blds[128*64];
  const int t    = threadIdx.x;
  const int lane = t & 63;
  const int w    = t >> 6;
  const int wr   = w >> 1, wc = w & 1;
  const int lr   = lane & 15, lk = lane >> 4;

  const int nwg = gridDim.x * gridDim.y;
  const int bid = blockIdx.y * gridDim.x + blockIdx.x;
  const int cpx = nwg >> 3;
  const int swz = (bid & 7) * cpx + (bid >> 3);
  const int bx  = swz % gridDim.x;
  const int by  = swz / gridDim.x;

  const long rowA0 = (long)by * 128;
  const long colB0 = (long)bx * 128;
  const u16* Ag = A  + rowA0 * lda;
  const u16* Bg = Bt + colB0 * K;
  const int srow = t >> 3, scol = t & 7;

#define STAGE(KT) do {                                                     \
    _Pragma("unroll")                                                      \
    for (int it = 0; it < 4; ++it) {                                       \
      int r  = it*32 + srow;                                               \
      int ca = (scol ^ (r & 7)) * 8;                                       \
      gld16(Ag + (long)r*lda + (long)(KT)*64 + ca, Alds + it*2048 + t*8);  \
      gld16(Bg + (long)r*K   + (long)(KT)*64 + ca, Blds + it*2048 + t*8);  \
    } } while(0)

  f32x4 acc[4][4];
#pragma unroll
  for (int m=0;m<4;m++)
#pragma unroll
    for (int n=0;n<4;n++) acc[m][n] = (f32x4){0.f,0.f,0.f,0.f};

  const int nk = K / 64;
  STAGE(0);
  __syncthreads();

  for (int kt = 0; kt < nk; ++kt) {
    bf8v af[4][2], bv[4][2];
#pragma unroll
    for (int m=0;m<4;m++)
#pragma unroll
      for (int ks=0;ks<2;ks++){
        int r  = wr*64 + m*16 + lr;
        int kb = (ks*32 + lk*8)*2;
        af[m][ks] = *(const bf8v*)((const char*)Alds + r*128 + (kb ^ ((r&7)<<4)));
      }
#pragma unroll
    for (int n=0;n<4;n++)
#pragma unroll
      for (int ks=0;ks<2;ks++){
        int r  = wc*64 + n*16 + lr;
        int kb = (ks*32 + lk*8)*2;
        bv[n][ks] = *(const bf8v*)((const char*)Blds + r*128 + (kb ^ ((r&7)<<4)));
      }
    __syncthreads();
    if (kt + 1 < nk) STAGE(kt + 1);
    __builtin_amdgcn_sched_barrier(0);
#pragma unroll
    for (int ks=0;ks<2;ks++)
#pragma unroll
      for (int m=0;m<4;m++)
#pragma unroll
        for (int n=0;n<4;n++)
          acc[m][n] = __builtin_amdgcn_mfma_f32_16x16x32_bf16(af[m][ks], bv[n][ks], acc[m][n], 0, 0, 0);
    if (kt + 1 < nk) __syncthreads();
  }
#undef STAGE

  u16*   Cb = (u16*)C1;
  float* Cf = (float*)C1;
#pragma unroll
  for (int m=0;m<4;m++){
    long row = rowA0 + wr*64 + m*16 + lk*4;
#pragma unroll
    for (int n=0;n<4;n++){
      int col = (int)colB0 + wc*64 + n*16 + lr;
      bool sec = (C2 != nullptr) && (col >= L_);
      float bvv = sec ? bias2[col - L_] : bias1[col];
      bool gel = gelu_flag && !sec;
#pragma unroll
      for (int rr=0; rr<4; ++rr){
        float v = acc[m][n][rr] + bvv;
        if (gel) {
          float u  = 0.7978845608028654f * (v + 0.044715f * v*v*v);
          float tu = fminf(fmaxf(2.f*u, -80.f), 80.f);
          float e  = __expf(tu);
          float th = (e - 1.f) / (e + 1.f);
          v = 0.5f * v * (1.f + th);
        }
        if (sec)          C2[(row+rr)*(long)L_ + (col - L_)] = f2bf(v);
        else if (f32out)  Cf[(row+rr)*(long)ldc + col] = v;
        else              Cb[(row+rr)*(long)ldc + col] = f2bf(v);
      }
    }
  }
}

// ============================================================================
// gates_fused: conv + block-diag gate GEMM + pointwise + chunk summaries.
// R9 change: Ae/Nr stores now go through a packed (ae|nr) u32 LDS buffer
// (XOR-swizzled) and a final vectorized u16x8 store phase (16 B/lane,
// fully coalesced) instead of scalar 2B global stores.
// ============================================================================
__global__ __launch_bounds__(256)
void gates_fused(const u16* __restrict__ Xlin, const float* __restrict__ cw,
                 const float* __restrict__ cb, const u16* __restrict__ Gt,
                 const float* __restrict__ gbias, const float* __restrict__ c8,
                 const int* __restrict__ pos,
                 u16* __restrict__ Ae, u16* __restrict__ Nr,
                 float* __restrict__ Ach, float* __restrict__ Hch)
{
  __shared__ __align__(16) char sm[16384 + 32768];   // [xc 16KB][xs/bs 32KB]
  const int t  = threadIdx.x;
  const int sc = blockIdx.x;      // seq chunk 0..63
  const int n  = blockIdx.y;      // head 0..15
  const int b  = blockIdx.z;      // batch
  const int s0 = sc*64;
  const long rowg0 = (long)b*S_ + s0;

  char* xc = sm;                  // [64][256B] swizzled conv output (A-operand + x)
  u16*  xs = (u16*)(sm + 16384);  // [67][128] linear staging of Xlin
  char* bs = sm + 16384;          // [128][256B] swizzled weights; later aeNr u32 buf

  // ---- 1) stage Xlin tile with halo (67 rows x 16 chunks of 8 ch)
  for (int it=0; it<5; ++it){
    int slot = it*256 + t;
    if (slot < 67*16){
      int i = slot >> 4, c = slot & 15;
      int s = s0 - 3 + i;
      u16x8 v = (u16x8){0,0,0,0,0,0,0,0};
      if (s >= 0)
        v = *(const u16x8*)(Xlin + ((long)b*S_ + s)*L_ + n*128 + c*8);
      *(u16x8*)(xs + i*128 + c*8) = v;
    }
  }
  __syncthreads();

  // ---- 2) conv -> xc (XOR-swizzled rows of 256B)
#pragma unroll
  for (int it=0; it<4; ++it){
    int slot = it*256 + t;              // 64*16 = 1024 slots
    int row = slot >> 4, c = slot & 15;
    int d0 = c*8;
    float a8[8];
#pragma unroll
    for (int j=0;j<8;j++) a8[j] = cb[n*128 + d0 + j];
#pragma unroll
    for (int k=0;k<4;k++){
      u16x8 xv = *(const u16x8*)(xs + (row+k)*128 + d0);
#pragma unroll
      for (int j=0;j<8;j++)
        a8[j] += bf2f(xv[j]) * cw[(n*128 + d0 + j)*4 + k];
    }
    u16x8 o;
#pragma unroll
    for (int j=0;j<8;j++) o[j] = f2bf(a8[j]);
    *(u16x8*)(xc + row*256 + ((d0*2) ^ ((row&7)<<4))) = o;
  }
  __syncthreads();   // conv reads of xs done; bs may overwrite

  const int w  = t >> 6;          // wave 0..3 -> rows w*16..+16
  const int lane = t & 63;
  const int lr = lane & 15, lk = lane >> 4;
  const int arow = w*16 + lr;

  // A-frags from xc (K=128 -> 4 k-steps)
  bf8v af[4];
#pragma unroll
  for (int ks=0;ks<4;ks++)
    af[ks] = *(const bf8v*)(xc + arow*256 + ((ks*64 + lk*16) ^ ((arow&7)<<4)));

  f32x4 aig[8], brg[8];
#pragma unroll
  for (int half=0; half<2; ++half){
    // ---- 3a) stage weight half (pre-swizzled source, linear LDS dest)
#pragma unroll
    for (int it=0; it<8; ++it){
      int slot = it*256 + t;            // 128*16 = 2048 slots
      int jr = slot >> 4, c = slot & 15;
      gld16(Gt + (size_t)(n*256 + half*128 + jr)*128 + (size_t)((c ^ (jr&7))*8),
            bs + slot*16);
    }
    __syncthreads();                    // drains vmcnt(0): weights landed
    // ---- 3b) MFMA
#pragma unroll
    for (int nf=0; nf<8; ++nf){
      f32x4 acc = (f32x4){0.f,0.f,0.f,0.f};
      int jrow = nf*16 + lr;
#pragma unroll
      for (int ks=0;ks<4;ks++){
        bf8v bv = *(const bf8v*)(bs + jrow*256 + ((ks*64 + lk*16) ^ ((jrow&7)<<4)));
        acc = __builtin_amdgcn_mfma_f32_16x16x32_bf16(af[ks], bv, acc, 0, 0, 0);
      }
      if (half==0) aig[nf] = acc; else brg[nf] = acc;
    }
    __syncthreads();                    // b-frag reads done before next overwrite
  }

  // ---- 4) pointwise epilogue -> packed (ae|nr) LDS; chunk summary in regs.
  // C/D layout: col = nf*16+lr, row = w*16 + lk*4 + rr.
  u32* aeNr = (u32*)bs;                 // [64 rows][128 ch] u32, ch XOR-swizzled per row
  bool rst[4];
#pragma unroll
  for (int rr=0; rr<4; ++rr) rst[rr] = (pos[rowg0 + w*16 + lk*4 + rr] == 0);

  float Awv[8], hwv[8];                 // per-nf wave-segment summaries (lk==0 lanes)
#pragma unroll
  for (int nf=0; nf<8; ++nf){
    int dl = nf*16 + lr;
    float gb1 = gbias[n*256 + dl];
    float gb2 = gbias[n*256 + 128 + dl];
    float cc8 = c8[n*128 + dl];
    float Aseg = 1.f, hseg = 0.f;       // ordered scan over rr = rows lk*4..+3
#pragma unroll
    for (int rr=0; rr<4; ++rr){
      int row = w*16 + lk*4 + rr;
      float ig = 1.f / (1.f + __expf(-(aig[nf][rr] + gb1)));
      float rg = 1.f / (1.f + __expf(-(brg[nf][rr] + gb2)));
      float la = cc8 * rg;
      float a  = __expf(la);
      float mult = rst[rr] ? 1.f : sqrtf(fmaxf(1.f - __expf(2.f*la), 0.f));
      u16 xv = *(const u16*)(xc + row*256 + ((dl*2) ^ ((row&7)<<4)));
      float x = bf2f(xv);
      u16 nr16 = f2bf(x * ig * mult);
      u16 ae16 = rst[rr] ? (u16)0 : f2bf(a);
      float nrv = bf2f(nr16);
      float aev = bf2f(ae16);
      aeNr[row*128 + (dl ^ ((row&7)<<4))] = (u32)ae16 | ((u32)nr16 << 16);
      hseg = fmaf(aev, hseg, nrv);
      Aseg *= aev;
    }
    // ordered compose across lk (4-row segments -> 16-row wave segment)
    {
      float Ap = __shfl_xor(Aseg, 16);
      float hp = __shfl_xor(hseg, 16);
      bool low = ((lk & 1) == 0);
      float Alo = low ? Aseg : Ap, Ahi = low ? Ap : Aseg;
      float hlo = low ? hseg : hp, hhi = low ? hp : hseg;
      Aseg = Alo * Ahi; hseg = fmaf(Ahi, hlo, hhi);
      Ap = __shfl_xor(Aseg, 32);
      hp = __shfl_xor(hseg, 32);
      low = ((lk & 2) == 0);
      Alo = low ? Aseg : Ap; Ahi = low ? Ap : Aseg;
      hlo = low ? hseg : hp; hhi = low ? hp : hseg;
      Aseg = Alo * Ahi; hseg = fmaf(Ahi, hlo, hhi);
    }
    Awv[nf] = Aseg; hwv[nf] = hseg;
  }
  __syncthreads();                      // all xv reads + aeNr writes done

  // wave summaries -> xc region (now dead)
  float* wsA = (float*)xc;              // [4 waves][128 ch]
  float* wsh = (float*)(xc + 2048);
  if (lk == 0){
#pragma unroll
    for (int nf=0; nf<8; ++nf){
      wsA[w*128 + nf*16 + lr] = Awv[nf];
      wsh[w*128 + nf*16 + lr] = hwv[nf];
    }
  }
  __syncthreads();

  if (t < 128){
    float A = wsA[t], h = wsh[t];
#pragma unroll
    for (int ww=1; ww<4; ++ww){
      float Aw = wsA[ww*128 + t], hw = wsh[ww*128 + t];
      h = fmaf(Aw, h, hw);
      A *= Aw;
    }
    long o = ((long)b*NC_ + sc)*L_ + n*128 + t;
    Ach[o] = A; Hch[o] = h;
  }

  // ---- 5) vectorized Ae/Nr stores: 1024 octets each, 4 per thread, 16B/lane.
#pragma unroll
  for (int ps=0; ps<4; ++ps){
    int o  = ps*256 + t;
    int r  = o >> 4, c8 = o & 15;
    int lb = r*128 + ((c8*8) ^ ((r&7)<<4));
    u32 v[8];
    *(f32x4*)&v[0] = *(const f32x4*)&aeNr[lb];
    *(f32x4*)&v[4] = *(const f32x4*)&aeNr[lb + 4];
    u16x8 ae8, nr8;
#pragma unroll
    for (int j=0;j<8;j++){ ae8[j] = (u16)(v[j] & 0xFFFFu); nr8[j] = (u16)(v[j] >> 16); }
    long gro = (rowg0 + r)*L_ + n*128 + c8*8;
    *(u16x8*)(Ae + gro) = ae8;
    *(u16x8*)(Nr + gro) = nr8;
  }
}

// ============================================================================
// prep_all (verified R8): transposes + gate-pack + X->bf16 in one launch
// ============================================================================
__global__ __launch_bounds__(256)
void prep_all(const float* __restrict__ Wy, const float* __restrict__ Wx,
              const float* __restrict__ Wout,
              u16* __restrict__ WyT, u16* __restrict__ WxT, u16* __restrict__ WoT,
              const float* __restrict__ igw, const float* __restrict__ rgw,
              const float* __restrict__ igb, const float* __restrict__ rgb,
              const float* __restrict__ rec, u16* __restrict__ Gt,
              float* __restrict__ gbias, float* __restrict__ c8,
              const float* __restrict__ X, u16* __restrict__ Xb)
{
  const int bidg = blockIdx.x;
  const int t = threadIdx.x;
  if (bidg < 3072) {
    int z   = bidg >> 10;
    int rem = bidg & 1023;
    const float* in  = (z == 0) ? Wy  : (z == 1) ? Wx  : Wout;
    u16*         out = (z == 0) ? WyT : (z == 1) ? WxT : WoT;
    const int R = 2048, C = 2048;
    __shared__ float tile[64][65];
    int tc = (rem & 31) * 64, tr = (rem >> 5) * 64;
    int r  = t >> 2, c0 = (t & 3) * 16;
#pragma unroll
    for (int i=0;i<4;i++)
      *(f32x4*)(&tile[r][c0 + i*4]) = *(const f32x4*)(in + (long)(tr+r)*C + tc + c0 + i*4);
    __syncthreads();
    int nl = t >> 2;
#pragma unroll
    for (int it=0; it<2; ++it){
      int g = (t & 3) + it*4;
      u16x8 o;
#pragma unroll
      for (int e=0;e<8;e++) o[e] = f2bf(tile[g*8+e][nl]);
      *(u16x8*)(out + (long)(tc+nl)*R + tr + g*8) = o;
    }
  } else if (bidg < 5120) {
    int idx = (bidg - 3072)*256 + t;       // NH_*256*128 = 524288
    int d = idx & 127, g = idx >> 7;
    int n = g >> 8, j = g & 255;
    float v = (j < 128) ? igw[(n*128 + d)*128 + j] : rgw[(n*128 + d)*128 + (j-128)];
    Gt[idx] = f2bf(v);
    if (idx < NH_*256) {
      int nn = idx >> 8, jj = idx & 255;
      gbias[idx] = (jj < 128) ? igb[nn*128 + jj] : rgb[nn*128 + jj - 128];
    }
    if (idx < L_) c8[idx] = -8.f * log1pf(__expf(rec[idx]));
  } else {
    long idx = (long)(bidg - 5120)*256 + t;
    f32x4 a = *(const f32x4*)(X + idx*8);
    f32x4 b = *(const f32x4*)(X + idx*8 + 4);
    u16x8 o;
#pragma unroll
    for (int e=0;e<4;e++){ o[e] = f2bf(a[e]); o[4+e] = f2bf(b[e]); }
    *(u16x8*)(Xb + idx*8) = o;
  }
}

// ---------------- scan3 (R9: vectorized, 4 ch/thread): carry + recompute + Z = h*y ---------
// grid 256 blocks x 256 thr; block = (batch, chunk c [reversed], half); thread
// handles 4 contiguous channels -> 8B/lane loads, fully coalesced.
__global__ __launch_bounds__(256)
void scan3(const u16* __restrict__ Ae, const u16* __restrict__ Nr,
           const float* __restrict__ Ach, const float* __restrict__ Hch,
           const u16* __restrict__ Y, u16* __restrict__ Z)
{
  const int t   = threadIdx.x;
  const int bid = blockIdx.x;
  const int b   = bid >> 7;
  const int rem = bid & 127;
  const int c   = (NC_-1) - (rem >> 1);        // long-carry blocks first
  const int l0  = ((rem & 1)*256 + t)*4;       // channel base (4 ch/thread)

  float h0=0.f, h1=0.f, h2=0.f, h3=0.f;
#pragma unroll 4
  for (int cc = 0; cc < c; ++cc){
    long o = ((long)b*NC_ + cc)*L_ + l0;
    f32x4 Av = *(const f32x4*)(Ach + o);
    f32x4 Hv = *(const f32x4*)(Hch + o);
    h0 = fmaf(Av[0], h0, Hv[0]);
    h1 = fmaf(Av[1], h1, Hv[1]);
    h2 = fmaf(Av[2], h2, Hv[2]);
    h3 = fmaf(Av[3], h3, Hv[3]);
  }
  long base = ((long)b*S_ + (long)c*CS_)*L_ + l0;
#pragma unroll 8
  for (int s=0; s<CS_; ++s){
    long o = base + (long)s*L_;
    u16x4 av = *(const u16x4*)(Ae + o);
    u16x4 nv = *(const u16x4*)(Nr + o);
    u16x4 yv = *(const u16x4*)(Y + o);
    u16x4 zv;
    h0 = fmaf(bf2f(av[0]), h0, bf2f(nv[0]));  zv[0] = f2bf(h0 * bf2f(yv[0]));
    h1 = fmaf(bf2f(av[1]), h1, bf2f(nv[1]));  zv[1] = f2bf(h1 * bf2f(yv[1]));
    h2 = fmaf(bf2f(av[2]), h2, bf2f(nv[2]));  zv[2] = f2bf(h2 * bf2f(yv[2]));
    h3 = fmaf(bf2f(av[3]), h3, bf2f(nv[3]));  zv[3] = f2bf(h3 * bf2f(yv[3]));
    *(u16x4*)(Z + o) = zv;
  }
}

// ---------------- launch ----------------
extern "C" void kernel_launch(void* const* d_in, const int* in_sizes, int n_in,
                              void* d_out, int out_size, void* d_ws, size_t ws_size,
                              hipStream_t stream)
{
  (void)in_sizes; (void)n_in; (void)out_size; (void)ws_size;
  const float* X    = (const float*)d_in[0];
  const float* Wy   = (const float*)d_in[1];
  const float* by   = (const float*)d_in[2];
  const float* Wx   = (const float*)d_in[3];
  const float* bx   = (const float*)d_in[4];
  const float* cw   = (const float*)d_in[5];
  const float* cb   = (const float*)d_in[6];
  const float* rec  = (const float*)d_in[7];
  const float* igw  = (const float*)d_in[8];
  const float* igb  = (const float*)d_in[9];
  const float* rgw  = (const float*)d_in[10];
  const float* rgb  = (const float*)d_in[11];
  const float* Wout = (const float*)d_in[12];
  const float* bout = (const float*)d_in[13];
  const int*   pos  = (const int*)d_in[14];
  float* out = (float*)d_out;   // reference output dtype is float32

  char* ws = (char*)d_ws;
  size_t o_Xbf  = 0;
  size_t o_Xlin = o_Xbf  + (size_t)M_*H_*2;
  size_t o_WyT  = o_Xlin + (size_t)M_*L_*2;           // WyT then WxT contiguous => fused Bt
  size_t o_WxT  = o_WyT  + (size_t)H_*L_*2;
  size_t o_WoT  = o_WxT  + (size_t)H_*L_*2;
  size_t o_Gt   = o_WoT  + (size_t)L_*H_*2;
  size_t o_gb   = o_Gt   + (size_t)NH_*256*128*2;
  size_t o_c8   = o_gb   + 4096*4;
  size_t o_Y    = o_c8   + 2048*4;
  size_t o_xc   = o_Y    + (size_t)M_*L_*2;           // Z buffer region
  size_t o_Ae   = o_xc   + (size_t)M_*L_*2;
  size_t o_Nr   = o_Ae   + (size_t)M_*L_*2;
  size_t o_Ach  = o_Nr   + (size_t)M_*L_*2;
  size_t o_Hch  = o_Ach  + (size_t)B_*NC_*L_*4;

  u16*   Xbf   = (u16*)(ws + o_Xbf);
  u16*   Xlin  = (u16*)(ws + o_Xlin);
  u16*   WyT   = (u16*)(ws + o_WyT);
  u16*   WxT   = (u16*)(ws + o_WxT);
  u16*   WoT   = (u16*)(ws + o_WoT);
  u16*   Gt    = (u16*)(ws + o_Gt);
  float* gbias = (float*)(ws + o_gb);
  float* c8    = (float*)(ws + o_c8);
  u16*   Y     = (u16*)(ws + o_Y);
  u16*   Z     = (u16*)(ws + o_xc);
  u16*   Ae    = (u16*)(ws + o_Ae);
  u16*   Nr    = (u16*)(ws + o_Nr);
  float* Ach   = (float*)(ws + o_Ach);
  float* Hch   = (float*)(ws + o_Hch);

  dim3 blk(256);
  // merged prep
  prep_all<<<dim3(13312), blk, 0, stream>>>(Wy, Wx, Wout, WyT, WxT, WoT,
                                            igw, rgw, igb, rgb, rec, Gt, gbias, c8,
                                            X, Xbf);
  // fused y+x linears (verified 2-phase): Bt = [WyT ; WxT], N=4096
  gemm_bf16<<<dim3(32,64), blk, 0, stream>>>(Xbf, H_, WyT, H_, by, bx, Y, Xlin, L_, 1, 0);
  // fused conv + block-diag gate GEMM + pointwise + chunk summaries
  gates_fused<<<dim3(NC_, NH_, B_), blk, 0, stream>>>(Xlin, cw, cb, Gt, gbias, c8, pos,
                                                      Ae, Nr, Ach, Hch);
  // carry prefix + recompute + Z = h*y (vectorized, c-reversed)
  scan3<<<dim3(256), blk, 0, stream>>>(Ae, Nr, Ach, Hch, Y, Z);
  // output projection (verified 2-phase) into d_out (fp32)
  gemm_bf16<<<dim3(16,64), blk, 0, stream>>>(Z, L_, WoT, L_, bout, bout, out, nullptr, H_, 0, 1);
}

// Round 11
// 387.251 us; speedup vs baseline: 1.3329x; 1.0430x over previous
//
#include <hip/hip_runtime.h>
#include <cstdint>
#include <cstddef>

// ---------------- problem constants ----------------
#define B_  2
#define S_  4096
#define H_  2048
#define L_  2048
#define NH_ 16
#define M_  (B_*S_)     // 8192 rows
#define NC_ 64          // scan chunks
#define CS_ 64          // chunk size (NC_*CS_ == S_)

typedef unsigned short u16;
typedef unsigned int   u32;
typedef short  bf8v  __attribute__((ext_vector_type(8)));   // 8 bf16 as raw shorts (MFMA operand)
typedef u16    u16x8 __attribute__((ext_vector_type(8)));
typedef u16    u16x4 __attribute__((ext_vector_type(4)));
typedef float  f32x4 __attribute__((ext_vector_type(4)));

__device__ __forceinline__ float bf2f(u16 u){
  union { unsigned i; float f; } v; v.i = ((unsigned)u) << 16; return v.f;
}
__device__ __forceinline__ u16 f2bf(float f){
  union { float f; unsigned i; } v; v.f = f;
  unsigned u = v.i;
  return (u16)((u + 0x7FFFu + ((u >> 16) & 1u)) >> 16);   // RNE
}
__device__ __forceinline__ float bfr(float f){ return bf2f(f2bf(f)); }  // round to bf16
__device__ __forceinline__ float frcp(float x){ return __builtin_amdgcn_rcpf(x); }   // v_rcp_f32 (~1ulp)
__device__ __forceinline__ float fsqrt(float x){ return __builtin_amdgcn_sqrtf(x); } // v_sqrt_f32
__device__ __forceinline__ void gld16(const void* g, void* l){
  __builtin_amdgcn_global_load_lds((const __attribute__((address_space(1))) void*)g,
                                   (__attribute__((address_space(3))) void*)l, 16, 0, 0);
}

// ---------------- GEMM: C[M,N] = A[M,K](bf16) @ Bt[N,K](bf16)^T, + bias, opt gelu ----------
// VERIFIED (rounds 2/3/6/7/8/10). BM=BN=128, BK=64, 256 thr (4 waves 2x2), 4x4 16x16x32 frags.
// Per K-step: ds_read all frags -> barrier -> issue next-tile global_load_lds -> MFMA
// (prefetch lands under MFMA) -> syncthreads. XCD M-band swizzle for L2 residency.
// 8 blocks/CU give the TLP that hides staging latency (the 256^2 1-block/CU
// experiments R4/R5/R9 all converged to schedule-invariant ~2.5x slower).
// R11: gelu tanh uses v_rcp instead of precise div (epilogue VALU cut).
__global__ __launch_bounds__(256)
void gemm_bf16(const u16* __restrict__ A, int lda,
               const u16* __restrict__ Bt, int K,
               const float* __restrict__ bias1, const float* __restrict__ bias2,
               void* __restrict__ C1, u16* __restrict__ C2, int ldc,
               int gelu_flag, int f32out)
{
  __shared__ u16 Alds[128*64];
  __shared__ u16 Blds[128*64];
  const int t    = threadIdx.x;
  const int lane = t & 63;
  const int w    = t >> 6;
  const int wr   = w >> 1, wc = w & 1;
  const int lr   = lane & 15, lk = lane >> 4;

  const int nwg = gridDim.x * gridDim.y;
  const int bid = blockIdx.y * gridDim.x + blockIdx.x;
  const int cpx = nwg >> 3;
  const int swz = (bid & 7) * cpx + (bid >> 3);
  const int bx  = swz % gridDim.x;
  const int by  = swz / gridDim.x;

  const long rowA0 = (long)by * 128;
  const long colB0 = (long)bx * 128;
  const u16* Ag = A  + rowA0 * lda;
  const u16* Bg = Bt + colB0 * K;
  const int srow = t >> 3, scol = t & 7;

#define STAGE(KT) do {                                                     \
    _Pragma("unroll")                                                      \
    for (int it = 0; it < 4; ++it) {                                       \
      int r  = it*32 + srow;                                               \
      int ca = (scol ^ (r & 7)) * 8;                                       \
      gld16(Ag + (long)r*lda + (long)(KT)*64 + ca, Alds + it*2048 + t*8);  \
      gld16(Bg + (long)r*K   + (long)(KT)*64 + ca, Blds + it*2048 + t*8);  \
    } } while(0)

  f32x4 acc[4][4];
#pragma unroll
  for (int m=0;m<4;m++)
#pragma unroll
    for (int n=0;n<4;n++) acc[m][n] = (f32x4){0.f,0.f,0.f,0.f};

  const int nk = K / 64;
  STAGE(0);
  __syncthreads();

  for (int kt = 0; kt < nk; ++kt) {
    bf8v af[4][2], bv[4][2];
#pragma unroll
    for (int m=0;m<4;m++)
#pragma unroll
      for (int ks=0;ks<2;ks++){
        int r  = wr*64 + m*16 + lr;
        int kb = (ks*32 + lk*8)*2;
        af[m][ks] = *(const bf8v*)((const char*)Alds + r*128 + (kb ^ ((r&7)<<4)));
      }
#pragma unroll
    for (int n=0;n<4;n++)
#pragma unroll
      for (int ks=0;ks<2;ks++){
        int r  = wc*64 + n*16 + lr;
        int kb = (ks*32 + lk*8)*2;
        bv[n][ks] = *(const bf8v*)((const char*)Blds + r*128 + (kb ^ ((r&7)<<4)));
      }
    __syncthreads();
    if (kt + 1 < nk) STAGE(kt + 1);
    __builtin_amdgcn_sched_barrier(0);
#pragma unroll
    for (int ks=0;ks<2;ks++)
#pragma unroll
      for (int m=0;m<4;m++)
#pragma unroll
        for (int n=0;n<4;n++)
          acc[m][n] = __builtin_amdgcn_mfma_f32_16x16x32_bf16(af[m][ks], bv[n][ks], acc[m][n], 0, 0, 0);
    if (kt + 1 < nk) __syncthreads();
  }
#undef STAGE

  u16*   Cb = (u16*)C1;
  float* Cf = (float*)C1;
#pragma unroll
  for (int m=0;m<4;m++){
    long row = rowA0 + wr*64 + m*16 + lk*4;
#pragma unroll
    for (int n=0;n<4;n++){
      int col = (int)colB0 + wc*64 + n*16 + lr;
      bool sec = (C2 != nullptr) && (col >= L_);
      float bvv = sec ? bias2[col - L_] : bias1[col];
      bool gel = gelu_flag && !sec;
#pragma unroll
      for (int rr=0; rr<4; ++rr){
        float v = acc[m][n][rr] + bvv;
        if (gel) {
          float u  = 0.7978845608028654f * (v + 0.044715f * v*v*v);
          float tu = fminf(fmaxf(2.f*u, -80.f), 80.f);
          float e  = __expf(tu);
          float th = (e - 1.f) * frcp(e + 1.f);
          v = 0.5f * v * (1.f + th);
        }
        if (sec)          C2[(row+rr)*(long)L_ + (col - L_)] = f2bf(v);
        else if (f32out)  Cf[(row+rr)*(long)ldc + col] = v;
        else              Cb[(row+rr)*(long)ldc + col] = f2bf(v);
      }
    }
  }
}

// ============================================================================
// gates_fused: conv + block-diag gate GEMM + pointwise + chunk summaries.
// R11: pointwise fast-math — sigmoid via v_rcp, exp(2la) -> a*a (identity),
// sqrt via v_sqrt. All results round to bf16, drift << threshold.
// ============================================================================
__global__ __launch_bounds__(256)
void gates_fused(const u16* __restrict__ Xlin, const float* __restrict__ cw,
                 const float* __restrict__ cb, const u16* __restrict__ Gt,
                 const float* __restrict__ gbias, const float* __restrict__ c8,
                 const int* __restrict__ pos,
                 u16* __restrict__ Ae, u16* __restrict__ Nr,
                 float* __restrict__ Ach, float* __restrict__ Hch)
{
  __shared__ __align__(16) char sm[16384 + 32768];   // [xc 16KB][xs/bs 32KB]
  const int t  = threadIdx.x;
  const int sc = blockIdx.x;      // seq chunk 0..63
  const int n  = blockIdx.y;      // head 0..15
  const int b  = blockIdx.z;      // batch
  const int s0 = sc*64;
  const long rowg0 = (long)b*S_ + s0;

  char* xc = sm;                  // [64][256B] swizzled conv output (A-operand + x)
  u16*  xs = (u16*)(sm + 16384);  // [67][128] linear staging of Xlin
  char* bs = sm + 16384;          // [128][256B] swizzled weights; later aeNr u32 buf

  // ---- 1) stage Xlin tile with halo (67 rows x 16 chunks of 8 ch)
  for (int it=0; it<5; ++it){
    int slot = it*256 + t;
    if (slot < 67*16){
      int i = slot >> 4, c = slot & 15;
      int s = s0 - 3 + i;
      u16x8 v = (u16x8){0,0,0,0,0,0,0,0};
      if (s >= 0)
        v = *(const u16x8*)(Xlin + ((long)b*S_ + s)*L_ + n*128 + c*8);
      *(u16x8*)(xs + i*128 + c*8) = v;
    }
  }
  __syncthreads();

  // ---- 2) conv -> xc (XOR-swizzled rows of 256B)
#pragma unroll
  for (int it=0; it<4; ++it){
    int slot = it*256 + t;              // 64*16 = 1024 slots
    int row = slot >> 4, c = slot & 15;
    int d0 = c*8;
    float a8[8];
#pragma unroll
    for (int j=0;j<8;j++) a8[j] = cb[n*128 + d0 + j];
#pragma unroll
    for (int k=0;k<4;k++){
      u16x8 xv = *(const u16x8*)(xs + (row+k)*128 + d0);
#pragma unroll
      for (int j=0;j<8;j++)
        a8[j] += bf2f(xv[j]) * cw[(n*128 + d0 + j)*4 + k];
    }
    u16x8 o;
#pragma unroll
    for (int j=0;j<8;j++) o[j] = f2bf(a8[j]);
    *(u16x8*)(xc + row*256 + ((d0*2) ^ ((row&7)<<4))) = o;
  }
  __syncthreads();   // conv reads of xs done; bs may overwrite

  const int w  = t >> 6;          // wave 0..3 -> rows w*16..+16
  const int lane = t & 63;
  const int lr = lane & 15, lk = lane >> 4;
  const int arow = w*16 + lr;

  // A-frags from xc (K=128 -> 4 k-steps)
  bf8v af[4];
#pragma unroll
  for (int ks=0;ks<4;ks++)
    af[ks] = *(const bf8v*)(xc + arow*256 + ((ks*64 + lk*16) ^ ((arow&7)<<4)));

  f32x4 aig[8], brg[8];
#pragma unroll
  for (int half=0; half<2; ++half){
    // ---- 3a) stage weight half (pre-swizzled source, linear LDS dest)
#pragma unroll
    for (int it=0; it<8; ++it){
      int slot = it*256 + t;            // 128*16 = 2048 slots
      int jr = slot >> 4, c = slot & 15;
      gld16(Gt + (size_t)(n*256 + half*128 + jr)*128 + (size_t)((c ^ (jr&7))*8),
            bs + slot*16);
    }
    __syncthreads();                    // drains vmcnt(0): weights landed
    // ---- 3b) MFMA
#pragma unroll
    for (int nf=0; nf<8; ++nf){
      f32x4 acc = (f32x4){0.f,0.f,0.f,0.f};
      int jrow = nf*16 + lr;
#pragma unroll
      for (int ks=0;ks<4;ks++){
        bf8v bv = *(const bf8v*)(bs + jrow*256 + ((ks*64 + lk*16) ^ ((jrow&7)<<4)));
        acc = __builtin_amdgcn_mfma_f32_16x16x32_bf16(af[ks], bv, acc, 0, 0, 0);
      }
      if (half==0) aig[nf] = acc; else brg[nf] = acc;
    }
    __syncthreads();                    // b-frag reads done before next overwrite
  }

  // ---- 4) pointwise epilogue -> packed (ae|nr) LDS; chunk summary in regs.
  // C/D layout: col = nf*16+lr, row = w*16 + lk*4 + rr.
  u32* aeNr = (u32*)bs;                 // [64 rows][128 ch] u32, ch XOR-swizzled per row
  bool rst[4];
#pragma unroll
  for (int rr=0; rr<4; ++rr) rst[rr] = (pos[rowg0 + w*16 + lk*4 + rr] == 0);

  float Awv[8], hwv[8];                 // per-nf wave-segment summaries (lk==0 lanes)
#pragma unroll
  for (int nf=0; nf<8; ++nf){
    int dl = nf*16 + lr;
    float gb1 = gbias[n*256 + dl];
    float gb2 = gbias[n*256 + 128 + dl];
    float cc8 = c8[n*128 + dl];
    float Aseg = 1.f, hseg = 0.f;       // ordered scan over rr = rows lk*4..+3
#pragma unroll
    for (int rr=0; rr<4; ++rr){
      int row = w*16 + lk*4 + rr;
      float ig = frcp(1.f + __expf(-(aig[nf][rr] + gb1)));
      float rg = frcp(1.f + __expf(-(brg[nf][rr] + gb2)));
      float la = cc8 * rg;
      float a  = __expf(la);
      float mult = rst[rr] ? 1.f : fsqrt(fmaxf(1.f - a*a, 0.f));  // exp(2la) == a^2
      u16 xv = *(const u16*)(xc + row*256 + ((dl*2) ^ ((row&7)<<4)));
      float x = bf2f(xv);
      u16 nr16 = f2bf(x * ig * mult);
      u16 ae16 = rst[rr] ? (u16)0 : f2bf(a);
      float nrv = bf2f(nr16);
      float aev = bf2f(ae16);
      aeNr[row*128 + (dl ^ ((row&7)<<4))] = (u32)ae16 | ((u32)nr16 << 16);
      hseg = fmaf(aev, hseg, nrv);
      Aseg *= aev;
    }
    // ordered compose across lk (4-row segments -> 16-row wave segment)
    {
      float Ap = __shfl_xor(Aseg, 16);
      float hp = __shfl_xor(hseg, 16);
      bool low = ((lk & 1) == 0);
      float Alo = low ? Aseg : Ap, Ahi = low ? Ap : Aseg;
      float hlo = low ? hseg : hp, hhi = low ? hp : hseg;
      Aseg = Alo * Ahi; hseg = fmaf(Ahi, hlo, hhi);
      Ap = __shfl_xor(Aseg, 32);
      hp = __shfl_xor(hseg, 32);
      low = ((lk & 2) == 0);
      Alo = low ? Aseg : Ap; Ahi = low ? Ap : Aseg;
      hlo = low ? hseg : hp; hhi = low ? hp : hseg;
      Aseg = Alo * Ahi; hseg = fmaf(Ahi, hlo, hhi);
    }
    Awv[nf] = Aseg; hwv[nf] = hseg;
  }
  __syncthreads();                      // all xv reads + aeNr writes done

  // wave summaries -> xc region (now dead)
  float* wsA = (float*)xc;              // [4 waves][128 ch]
  float* wsh = (float*)(xc + 2048);
  if (lk == 0){
#pragma unroll
    for (int nf=0; nf<8; ++nf){
      wsA[w*128 + nf*16 + lr] = Awv[nf];
      wsh[w*128 + nf*16 + lr] = hwv[nf];
    }
  }
  __syncthreads();

  if (t < 128){
    float A = wsA[t], h = wsh[t];
#pragma unroll
    for (int ww=1; ww<4; ++ww){
      float Aw = wsA[ww*128 + t], hw = wsh[ww*128 + t];
      h = fmaf(Aw, h, hw);
      A *= Aw;
    }
    long o = ((long)b*NC_ + sc)*L_ + n*128 + t;
    Ach[o] = A; Hch[o] = h;
  }

  // ---- 5) vectorized Ae/Nr stores: 1024 octets each, 4 per thread, 16B/lane.
#pragma unroll
  for (int ps=0; ps<4; ++ps){
    int o  = ps*256 + t;
    int r  = o >> 4, c8 = o & 15;
    int lb = r*128 + ((c8*8) ^ ((r&7)<<4));
    u32 v[8];
    *(f32x4*)&v[0] = *(const f32x4*)&aeNr[lb];
    *(f32x4*)&v[4] = *(const f32x4*)&aeNr[lb + 4];
    u16x8 ae8, nr8;
#pragma unroll
    for (int j=0;j<8;j++){ ae8[j] = (u16)(v[j] & 0xFFFFu); nr8[j] = (u16)(v[j] >> 16); }
    long gro = (rowg0 + r)*L_ + n*128 + c8*8;
    *(u16x8*)(Ae + gro) = ae8;
    *(u16x8*)(Nr + gro) = nr8;
  }
}

// ============================================================================
// prep_all (verified R8): transposes + gate-pack + X->bf16 in one launch
// ============================================================================
__global__ __launch_bounds__(256)
void prep_all(const float* __restrict__ Wy, const float* __restrict__ Wx,
              const float* __restrict__ Wout,
              u16* __restrict__ WyT, u16* __restrict__ WxT, u16* __restrict__ WoT,
              const float* __restrict__ igw, const float* __restrict__ rgw,
              const float* __restrict__ igb, const float* __restrict__ rgb,
              const float* __restrict__ rec, u16* __restrict__ Gt,
              float* __restrict__ gbias, float* __restrict__ c8,
              const float* __restrict__ X, u16* __restrict__ Xb)
{
  const int bidg = blockIdx.x;
  const int t = threadIdx.x;
  if (bidg < 3072) {
    int z   = bidg >> 10;
    int rem = bidg & 1023;
    const float* in  = (z == 0) ? Wy  : (z == 1) ? Wx  : Wout;
    u16*         out = (z == 0) ? WyT : (z == 1) ? WxT : WoT;
    const int R = 2048, C = 2048;
    __shared__ float tile[64][65];
    int tc = (rem & 31) * 64, tr = (rem >> 5) * 64;
    int r  = t >> 2, c0 = (t & 3) * 16;
#pragma unroll
    for (int i=0;i<4;i++)
      *(f32x4*)(&tile[r][c0 + i*4]) = *(const f32x4*)(in + (long)(tr+r)*C + tc + c0 + i*4);
    __syncthreads();
    int nl = t >> 2;
#pragma unroll
    for (int it=0; it<2; ++it){
      int g = (t & 3) + it*4;
      u16x8 o;
#pragma unroll
      for (int e=0;e<8;e++) o[e] = f2bf(tile[g*8+e][nl]);
      *(u16x8*)(out + (long)(tc+nl)*R + tr + g*8) = o;
    }
  } else if (bidg < 5120) {
    int idx = (bidg - 3072)*256 + t;       // NH_*256*128 = 524288
    int d = idx & 127, g = idx >> 7;
    int n = g >> 8, j = g & 255;
    float v = (j < 128) ? igw[(n*128 + d)*128 + j] : rgw[(n*128 + d)*128 + (j-128)];
    Gt[idx] = f2bf(v);
    if (idx < NH_*256) {
      int nn = idx >> 8, jj = idx & 255;
      gbias[idx] = (jj < 128) ? igb[nn*128 + jj] : rgb[nn*128 + jj - 128];
    }
    if (idx < L_) c8[idx] = -8.f * log1pf(__expf(rec[idx]));
  } else {
    long idx = (long)(bidg - 5120)*256 + t;
    f32x4 a = *(const f32x4*)(X + idx*8);
    f32x4 b = *(const f32x4*)(X + idx*8 + 4);
    u16x8 o;
#pragma unroll
    for (int e=0;e<4;e++){ o[e] = f2bf(a[e]); o[4+e] = f2bf(b[e]); }
    *(u16x8*)(Xb + idx*8) = o;
  }
}

// ---------------- scan3 (verified R10: vectorized, 4 ch/thread) ----------------
__global__ __launch_bounds__(256)
void scan3(const u16* __restrict__ Ae, const u16* __restrict__ Nr,
           const float* __restrict__ Ach, const float* __restrict__ Hch,
           const u16* __restrict__ Y, u16* __restrict__ Z)
{
  const int t   = threadIdx.x;
  const int bid = blockIdx.x;
  const int b   = bid >> 7;
  const int rem = bid & 127;
  const int c   = (NC_-1) - (rem >> 1);        // long-carry blocks first
  const int l0  = ((rem & 1)*256 + t)*4;       // channel base (4 ch/thread)

  float h0=0.f, h1=0.f, h2=0.f, h3=0.f;
#pragma unroll 4
  for (int cc = 0; cc < c; ++cc){
    long o = ((long)b*NC_ + cc)*L_ + l0;
    f32x4 Av = *(const f32x4*)(Ach + o);
    f32x4 Hv = *(const f32x4*)(Hch + o);
    h0 = fmaf(Av[0], h0, Hv[0]);
    h1 = fmaf(Av[1], h1, Hv[1]);
    h2 = fmaf(Av[2], h2, Hv[2]);
    h3 = fmaf(Av[3], h3, Hv[3]);
  }
  long base = ((long)b*S_ + (long)c*CS_)*L_ + l0;
#pragma unroll 8
  for (int s=0; s<CS_; ++s){
    long o = base + (long)s*L_;
    u16x4 av = *(const u16x4*)(Ae + o);
    u16x4 nv = *(const u16x4*)(Nr + o);
    u16x4 yv = *(const u16x4*)(Y + o);
    u16x4 zv;
    h0 = fmaf(bf2f(av[0]), h0, bf2f(nv[0]));  zv[0] = f2bf(h0 * bf2f(yv[0]));
    h1 = fmaf(bf2f(av[1]), h1, bf2f(nv[1]));  zv[1] = f2bf(h1 * bf2f(yv[1]));
    h2 = fmaf(bf2f(av[2]), h2, bf2f(nv[2]));  zv[2] = f2bf(h2 * bf2f(yv[2]));
    h3 = fmaf(bf2f(av[3]), h3, bf2f(nv[3]));  zv[3] = f2bf(h3 * bf2f(yv[3]));
    *(u16x4*)(Z + o) = zv;
  }
}

// ---------------- launch ----------------
extern "C" void kernel_launch(void* const* d_in, const int* in_sizes, int n_in,
                              void* d_out, int out_size, void* d_ws, size_t ws_size,
                              hipStream_t stream)
{
  (void)in_sizes; (void)n_in; (void)out_size; (void)ws_size;
  const float* X    = (const float*)d_in[0];
  const float* Wy   = (const float*)d_in[1];
  const float* by   = (const float*)d_in[2];
  const float* Wx   = (const float*)d_in[3];
  const float* bx   = (const float*)d_in[4];
  const float* cw   = (const float*)d_in[5];
  const float* cb   = (const float*)d_in[6];
  const float* rec  = (const float*)d_in[7];
  const float* igw  = (const float*)d_in[8];
  const float* igb  = (const float*)d_in[9];
  const float* rgw  = (const float*)d_in[10];
  const float* rgb  = (const float*)d_in[11];
  const float* Wout = (const float*)d_in[12];
  const float* bout = (const float*)d_in[13];
  const int*   pos  = (const int*)d_in[14];
  float* out = (float*)d_out;   // reference output dtype is float32

  char* ws = (char*)d_ws;
  size_t o_Xbf  = 0;
  size_t o_Xlin = o_Xbf  + (size_t)M_*H_*2;
  size_t o_WyT  = o_Xlin + (size_t)M_*L_*2;           // WyT then WxT contiguous => fused Bt
  size_t o_WxT  = o_WyT  + (size_t)H_*L_*2;
  size_t o_WoT  = o_WxT  + (size_t)H_*L_*2;
  size_t o_Gt   = o_WoT  + (size_t)L_*H_*2;
  size_t o_gb   = o_Gt   + (size_t)NH_*256*128*2;
  size_t o_c8   = o_gb   + 4096*4;
  size_t o_Y    = o_c8   + 2048*4;
  size_t o_xc   = o_Y    + (size_t)M_*L_*2;           // Z buffer region
  size_t o_Ae   = o_xc   + (size_t)M_*L_*2;
  size_t o_Nr   = o_Ae   + (size_t)M_*L_*2;
  size_t o_Ach  = o_Nr   + (size_t)M_*L_*2;
  size_t o_Hch  = o_Ach  + (size_t)B_*NC_*L_*4;

  u16*   Xbf   = (u16*)(ws + o_Xbf);
  u16*   Xlin  = (u16*)(ws + o_Xlin);
  u16*   WyT   = (u16*)(ws + o_WyT);
  u16*   WxT   = (u16*)(ws + o_WxT);
  u16*   WoT   = (u16*)(ws + o_WoT);
  u16*   Gt    = (u16*)(ws + o_Gt);
  float* gbias = (float*)(ws + o_gb);
  float* c8    = (float*)(ws + o_c8);
  u16*   Y     = (u16*)(ws + o_Y);
  u16*   Z     = (u16*)(ws + o_xc);
  u16*   Ae    = (u16*)(ws + o_Ae);
  u16*   Nr    = (u16*)(ws + o_Nr);
  float* Ach   = (float*)(ws + o_Ach);
  float* Hch   = (float*)(ws + o_Hch);

  dim3 blk(256);
  // merged prep
  prep_all<<<dim3(13312), blk, 0, stream>>>(Wy, Wx, Wout, WyT, WxT, WoT,
                                            igw, rgw, igb, rgb, rec, Gt, gbias, c8,
                                            X, Xbf);
  // fused y+x linears (verified 2-phase): Bt = [WyT ; WxT], N=4096
  gemm_bf16<<<dim3(32,64), blk, 0, stream>>>(Xbf, H_, WyT, H_, by, bx, Y, Xlin, L_, 1, 0);
  // fused conv + block-diag gate GEMM + pointwise + chunk summaries
  gates_fused<<<dim3(NC_, NH_, B_), blk, 0, stream>>>(Xlin, cw, cb, Gt, gbias, c8, pos,
                                                      Ae, Nr, Ach, Hch);
  // carry prefix + recompute + Z = h*y (vectorized, c-reversed)
  scan3<<<dim3(256), blk, 0, stream>>>(Ae, Nr, Ach, Hch, Y, Z);
  // output projection (verified 2-phase) into d_out (fp32)
  gemm_bf16<<<dim3(16,64), blk, 0, stream>>>(Z, L_, WoT, L_, bout, bout, out, nullptr, H_, 0, 1);
}